// Round 2
// baseline (226.592 us; speedup 1.0000x reference)
//
#include <hip/hip_runtime.h>
#include <hip/hip_bf16.h>

// Problem constants
#define BB 512   // batch
#define SS 96    // seq len
#define NN 64    // nodes
#define HH 512   // hidden
#define EE 512   // edges per graph

typedef __attribute__((ext_vector_type(8))) short short8;   // 8 bf16 (4 VGPRs)
typedef __attribute__((ext_vector_type(4))) float f32x4;    // MFMA acc
typedef unsigned short u16;

__device__ __forceinline__ u16 f2bf(float f) {
    union { float f; unsigned u; } v; v.f = f;
    return (u16)((v.u + 0x7FFFu + ((v.u >> 16) & 1u)) >> 16);   // RNE
}
__device__ __forceinline__ short8 ld8bf(const u16* p) { return *(const short8*)p; }
__device__ __forceinline__ short8 cvt8(const float* p) {       // 8 fp32 -> bf16 frag
    float4 a = *(const float4*)p, b = *(const float4*)(p + 4);
    short8 r;
    r[0] = (short)f2bf(a.x); r[1] = (short)f2bf(a.y);
    r[2] = (short)f2bf(a.z); r[3] = (short)f2bf(a.w);
    r[4] = (short)f2bf(b.x); r[5] = (short)f2bf(b.y);
    r[6] = (short)f2bf(b.z); r[7] = (short)f2bf(b.w);
    return r;
}
__device__ __forceinline__ ushort4 packbf(f32x4 a) {
    ushort4 u; u.x = f2bf(a[0]); u.y = f2bf(a[1]); u.z = f2bf(a[2]); u.w = f2bf(a[3]);
    return u;
}

// ---------------------------------------------------------------------------
// k_prep: weights -> bf16; conv weight reordered (n,kw) -> (kw,n).
// ---------------------------------------------------------------------------
__global__ __launch_bounds__(256) void k_prep(const float* __restrict__ W1,
                                              const float* __restrict__ W2,
                                              const float* __restrict__ cw,
                                              u16* __restrict__ W1b,
                                              u16* __restrict__ W2b,
                                              u16* __restrict__ Wcb) {
    const int i0 = blockIdx.x * 256 + threadIdx.x, stp = gridDim.x * 256;
    for (int i = i0; i < HH * SS; i += stp) W1b[i] = f2bf(W1[i]);
    for (int i = i0; i < SS * HH; i += stp) W2b[i] = f2bf(W2[i]);
    for (int i = i0; i < HH * 192; i += stp) {
        int h = i / 192, q = i % 192, n = q / 3, kw = q % 3;
        Wcb[h * 192 + kw * 64 + n] = f2bf(cw[i]);
    }
}

// ---------------------------------------------------------------------------
// k_gcn: one block of 512 threads (8 waves) per graph.  GCN1+relu+GCN2+adj
// ending in Hp [98][64] bf16 (circular-padded) written to workspace.
// (unchanged from round 1 — see comments there)
// ---------------------------------------------------------------------------
__global__ __launch_bounds__(512, 4) void k_gcn(const float* __restrict__ x,
                                                const int* __restrict__ ei,
                                                const u16* __restrict__ W1b,
                                                const float* __restrict__ b1,
                                                const u16* __restrict__ W2b,
                                                const float* __restrict__ b2,
                                                u16* __restrict__ HpG) {
    const int b = blockIdx.x, t = threadIdx.x;
    const int w = t >> 6, lane = t & 63, quad = lane >> 4, l16 = lane & 15;
    const int wg = w & 3, wh = w >> 2;

    __shared__ __align__(16) char smem[57344];
    u16*   As   = (u16*)smem;                 // [64][72]
    u16*   Gs   = (u16*)(smem + 9216);        // [64][104]
    u16*   H1   = (u16*)(smem + 22528);       // [2][64][72]
    u16*   Ts   = (u16*)(smem + 9216);        // overlay: [2][96][72]
    float* Asm  = (float*)(smem + 40960);     // [64][64]
    u16*   Hp   = (u16*)(smem + 40960);       // overlay: [98][72]
    int*   deg  = (int*)(smem + 9216);
    float* dinv = (float*)(smem + 9472);

    // ---- phase 0: normalized adjacency ----
    for (int i = t; i < 4096; i += 512) Asm[i] = 0.f;
    if (t < 64) deg[t] = 1;                         // self loop
    __syncthreads();
    const int* eb = ei + (size_t)b * 2 * EE;
    const int es = eb[t], ed = eb[EE + t];          // E == 512 == blockDim
    atomicAdd(&deg[ed], 1);
    __syncthreads();
    if (t < 64) dinv[t] = rsqrtf((float)deg[t]);
    __syncthreads();
    atomicAdd(&Asm[ed * 64 + es], dinv[es] * dinv[ed]);
    if (t < 64) atomicAdd(&Asm[t * 64 + t], dinv[t] * dinv[t]);
    __syncthreads();
    // As bf16 [64][72]
    for (int i = t; i < 1024; i += 512) {
        int n = i >> 4, m4 = (i & 15) * 4;
        f32x4 v = *(const f32x4*)(Asm + n * 64 + m4);
        *(ushort4*)(As + n * 72 + m4) = packbf(v);
    }
    __syncthreads();

    // ---- MFMA0: Gs[node][s] = X @ A^T  (wave: ngroup=wg, j in its s-half) ----
    {
        short8 bf0[2];
        #pragma unroll
        for (int kc = 0; kc < 2; ++kc)
            bf0[kc] = ld8bf(As + (wg * 16 + l16) * 72 + kc * 32 + quad * 8);
        const float* xb = x + (size_t)b * SS * NN;
        #pragma unroll
        for (int jj = 0; jj < 3; ++jj) {
            const int j = wh * 3 + jj;
            f32x4 acc = (f32x4){0.f, 0.f, 0.f, 0.f};
            #pragma unroll
            for (int kc = 0; kc < 2; ++kc) {
                short8 a = cvt8(xb + (j * 16 + l16) * 64 + kc * 32 + quad * 8);
                acc = __builtin_amdgcn_mfma_f32_16x16x32_bf16(a, bf0[kc], acc, 0, 0, 0);
            }
            // col=l16 -> node=wg*16+l16 ; row=quad*4+r -> s=j*16+quad*4+r
            *(ushort4*)(Gs + (wg * 16 + l16) * 104 + j * 16 + quad * 4) = packbf(acc);
        }
    }
    __syncthreads();   // Gs cols written by both s-halves; chunk loop reads all 96

    // ---- hidden-chunk loop: wave handles hc = wh*4 .. wh*4+3 (barrier-free) ----
    f32x4 accT[6];
    #pragma unroll
    for (int j = 0; j < 6; ++j) accT[j] = (f32x4){0.f, 0.f, 0.f, 0.f};

    short8 gb[3];
    #pragma unroll
    for (int kc = 0; kc < 3; ++kc)
        gb[kc] = ld8bf(Gs + (wg * 16 + l16) * 104 + kc * 32 + quad * 8);

    u16* H1w = H1 + wh * (64 * 72);
    #pragma unroll
    for (int hcc = 0; hcc < 4; ++hcc) {
        const int hc = wh * 4 + hcc;
        // MFMA1: C[h][node] -> H1w[node][h]
        #pragma unroll
        for (int hs = 0; hs < 4; ++hs) {
            f32x4 a1 = (f32x4){0.f, 0.f, 0.f, 0.f};
            #pragma unroll
            for (int kc = 0; kc < 3; ++kc) {
                short8 wa = ld8bf(W1b + (size_t)(hc * 64 + hs * 16 + l16) * 96 + kc * 32 + quad * 8);
                a1 = __builtin_amdgcn_mfma_f32_16x16x32_bf16(wa, gb[kc], a1, 0, 0, 0);
            }
            float4 bias = *(const float4*)(b1 + hc * 64 + hs * 16 + quad * 4);
            f32x4 r;
            r[0] = fmaxf(a1[0] + bias.x, 0.f); r[1] = fmaxf(a1[1] + bias.y, 0.f);
            r[2] = fmaxf(a1[2] + bias.z, 0.f); r[3] = fmaxf(a1[3] + bias.w, 0.f);
            *(ushort4*)(H1w + (wg * 16 + l16) * 72 + hs * 16 + quad * 4) = packbf(r);
        }
        // MFMA2: accT[node][s] += H1w @ W2c^T
        short8 ha[2];
        #pragma unroll
        for (int kc = 0; kc < 2; ++kc)
            ha[kc] = ld8bf(H1w + (wg * 16 + l16) * 72 + kc * 32 + quad * 8);
        #pragma unroll
        for (int j = 0; j < 6; ++j)
            #pragma unroll
            for (int kc = 0; kc < 2; ++kc) {
                short8 wb = ld8bf(W2b + (size_t)(j * 16 + l16) * HH + hc * 64 + kc * 32 + quad * 8);
                accT[j] = __builtin_amdgcn_mfma_f32_16x16x32_bf16(ha[kc], wb, accT[j], 0, 0, 0);
            }
    }

    // ---- Ts[wh][s][m] <- accT (overlay on Gs/H1: barrier first) ----
    __syncthreads();
    u16* Tsw = Ts + wh * (96 * 72);
    #pragma unroll
    for (int j = 0; j < 6; ++j)   // col=l16 -> s=j*16+l16 ; rows node=wg*16+quad*4+r
        *(ushort4*)(Tsw + (j * 16 + l16) * 72 + wg * 16 + quad * 4) = packbf(accT[j]);
    __syncthreads();

    // ---- MFMA3: Hp[s+1][n] = A @ (Ts0 + Ts1) + b2 ----
    {
        short8 af[2];
        #pragma unroll
        for (int kc = 0; kc < 2; ++kc)
            af[kc] = ld8bf(As + (wg * 16 + l16) * 72 + kc * 32 + quad * 8);
        #pragma unroll
        for (int jj = 0; jj < 3; ++jj) {
            const int j = wh * 3 + jj;
            f32x4 a3 = (f32x4){0.f, 0.f, 0.f, 0.f};
            #pragma unroll
            for (int h = 0; h < 2; ++h)
                #pragma unroll
                for (int kc = 0; kc < 2; ++kc) {
                    short8 tb = ld8bf(Ts + h * (96 * 72) + (j * 16 + l16) * 72 + kc * 32 + quad * 8);
                    a3 = __builtin_amdgcn_mfma_f32_16x16x32_bf16(af[kc], tb, a3, 0, 0, 0);
                }
            float bs = b2[j * 16 + l16];
            f32x4 r = {a3[0] + bs, a3[1] + bs, a3[2] + bs, a3[3] + bs};
            // col=l16 -> s=j*16+l16 ; rows n=wg*16+quad*4+r
            *(ushort4*)(Hp + (j * 16 + l16 + 1) * 72 + wg * 16 + quad * 4) = packbf(r);
        }
    }
    __syncthreads();

    // ---- store Hp -> global [98][64] with circular pad folded into the copy ----
    u16* hg = HpG + (size_t)b * (98 * 64);
    for (int i = t; i < 98 * 16; i += 512) {
        int r = i >> 4, c4 = (i & 15) * 4;
        int rs = (r == 0) ? 96 : ((r == 97) ? 1 : r);   // rows 1..96 = s 0..95
        *(ushort4*)(hg + r * 64 + c4) = *(const ushort4*)(Hp + rs * 72 + c4);
    }
}

// ---------------------------------------------------------------------------
// k_conv: grid (6, 512) = one block per (s-slice j, graph g).
// Round-2 change: MFMA fragments go to an LDS tile Osl[16][520] (f32), then a
// coalesced copy-out: consecutive lanes -> consecutive h, 1 KB contiguous per
// wave-store, non-temporal (streaming 100 MB; don't evict Wcb/Hp from L2).
// Previous direct fragment stores were 16 scattered 64B segments per wave
// (stride 2 KB) -> DRAM efficiency capped writes at ~1.4 TB/s.
// LDS: Hsl 2592 B + Osl 33280 B -> 4 blocks/CU.
// ---------------------------------------------------------------------------
__global__ __launch_bounds__(256, 4) void k_conv(const u16* __restrict__ HpG,
                                                 const u16* __restrict__ Wcb,
                                                 float* __restrict__ out) {
    const int j = blockIdx.x, g = blockIdx.y;
    const int t = threadIdx.x, w = t >> 6, lane = t & 63, quad = lane >> 4, l16 = lane & 15;

    __shared__ __align__(16) u16 Hsl[18 * 72];
    __shared__ __align__(16) float Osl[16 * 520];   // [s][h], pad 520 (~4-way max)
    const u16* hg = HpG + (size_t)g * (98 * 64) + j * (16 * 64);
    if (t < 144) {                 // 18 rows x 4 chunks of 16B
        int r = t >> 3, c8 = (t & 7) * 8;
        *(short8*)(Hsl + r * 72 + c8) = ld8bf(hg + r * 64 + c8);
    }
    __syncthreads();

    #pragma unroll
    for (int ht = 0; ht < 8; ++ht) {
        short8 wa[6];
        #pragma unroll
        for (int kc = 0; kc < 6; ++kc)
            wa[kc] = ld8bf(Wcb + (size_t)(ht * 64 + w * 16 + l16) * 192 + kc * 32 + quad * 8);
        f32x4 acc = (f32x4){0.f, 0.f, 0.f, 0.f};
        #pragma unroll
        for (int kc = 0; kc < 6; ++kc) {
            int kw = kc >> 1, nb = (kc & 1) * 32;
            short8 hb = ld8bf(Hsl + (l16 + kw) * 72 + nb + quad * 8);
            acc = __builtin_amdgcn_mfma_f32_16x16x32_bf16(wa[kc], hb, acc, 0, 0, 0);
        }
        // col=l16 -> s ; rows h=ht*64+w*16+quad*4+r  -> transpose via LDS
        *(f32x4*)(Osl + l16 * 520 + ht * 64 + w * 16 + quad * 4) = acc;
    }
    __syncthreads();

    // coalesced copy-out: wave writes 1 KB contiguous per iteration
    float* ob = out + (size_t)g * SS * HH + (size_t)(j * 16) * HH;
    #pragma unroll
    for (int it = 0; it < 8; ++it) {
        int idx = it * 256 + t;
        int s = idx >> 7, c4 = (idx & 127) << 2;      // 128 float4 per row
        f32x4 v = *(const f32x4*)(Osl + s * 520 + c4);
        __builtin_nontemporal_store(v, (f32x4*)(ob + (size_t)s * HH + c4));
    }
}

// ---------------------------------------------------------------------------
extern "C" void kernel_launch(void* const* d_in, const int* in_sizes, int n_in,
                              void* d_out, int out_size, void* d_ws, size_t ws_size,
                              hipStream_t stream) {
    const float* x  = (const float*)d_in[0];
    const int*   ei = (const int*)d_in[1];
    const float* W1 = (const float*)d_in[2];
    const float* b1 = (const float*)d_in[3];
    const float* W2 = (const float*)d_in[4];
    const float* b2 = (const float*)d_in[5];
    const float* cw = (const float*)d_in[6];
    float* out = (float*)d_out;

    char* wsp = (char*)d_ws;
    u16* W1b = (u16*)wsp;                    // 98,304 B
    u16* W2b = (u16*)(wsp + 98304);          // 98,304 B
    u16* Wcb = (u16*)(wsp + 196608);         // 196,608 B
    u16* HpG = (u16*)(wsp + 393216);         // 512*98*64*2 = 6,422,528 B

    k_prep<<<96, 256, 0, stream>>>(W1, W2, cw, W1b, W2b, Wcb);
    k_gcn <<<BB, 512, 0, stream>>>(x, ei, W1b, b1, W2b, b2, HpG);
    k_conv<<<dim3(6, BB), 256, 0, stream>>>(HpG, Wcb, out);
}

// Round 3
// 171.479 us; speedup vs baseline: 1.3214x; 1.3214x over previous
//
#include <hip/hip_runtime.h>
#include <hip/hip_bf16.h>

// Problem constants
#define BB 512   // batch
#define SS 96    // seq len
#define NN 64    // nodes
#define HH 512   // hidden
#define EE 512   // edges per graph

typedef __attribute__((ext_vector_type(8))) short short8;   // 8 bf16 (4 VGPRs)
typedef __attribute__((ext_vector_type(4))) float f32x4;    // MFMA acc
typedef unsigned short u16;

__device__ __forceinline__ u16 f2bf(float f) {
    union { float f; unsigned u; } v; v.f = f;
    return (u16)((v.u + 0x7FFFu + ((v.u >> 16) & 1u)) >> 16);   // RNE
}
__device__ __forceinline__ short8 ld8bf(const u16* p) { return *(const short8*)p; }
__device__ __forceinline__ short8 cvt8(const float* p) {       // 8 fp32 -> bf16 frag
    float4 a = *(const float4*)p, b = *(const float4*)(p + 4);
    short8 r;
    r[0] = (short)f2bf(a.x); r[1] = (short)f2bf(a.y);
    r[2] = (short)f2bf(a.z); r[3] = (short)f2bf(a.w);
    r[4] = (short)f2bf(b.x); r[5] = (short)f2bf(b.y);
    r[6] = (short)f2bf(b.z); r[7] = (short)f2bf(b.w);
    return r;
}
__device__ __forceinline__ ushort4 packbf(f32x4 a) {
    ushort4 u; u.x = f2bf(a[0]); u.y = f2bf(a[1]); u.z = f2bf(a[2]); u.w = f2bf(a[3]);
    return u;
}

// ---------------------------------------------------------------------------
// k_prep: weights -> bf16; conv weight reordered (n,kw) -> (kw,n).
// ---------------------------------------------------------------------------
__global__ __launch_bounds__(256) void k_prep(const float* __restrict__ W1,
                                              const float* __restrict__ W2,
                                              const float* __restrict__ cw,
                                              u16* __restrict__ W1b,
                                              u16* __restrict__ W2b,
                                              u16* __restrict__ Wcb) {
    const int i0 = blockIdx.x * 256 + threadIdx.x, stp = gridDim.x * 256;
    for (int i = i0; i < HH * SS; i += stp) W1b[i] = f2bf(W1[i]);
    for (int i = i0; i < SS * HH; i += stp) W2b[i] = f2bf(W2[i]);
    for (int i = i0; i < HH * 192; i += stp) {
        int h = i / 192, q = i % 192, n = q / 3, kw = q % 3;
        Wcb[h * 192 + kw * 64 + n] = f2bf(cw[i]);
    }
}

// ---------------------------------------------------------------------------
// k_all: FUSED, one block of 512 threads (8 waves) per graph.
// Round-3 structure = round-1 k_gcn phases (8-wave split: wg=w&3 node-group,
// wh=w>>2 hidden/s half) + round-0 conv phase fused back (split 8 ways:
// wc=w&3 h-sub, wt=w>>2 ht-group), direct fragment stores.
// Rationale: round-0 fused did GCN+conv+100MB stores in 74 us while the
// split kernels took 48+75 -> store drain overlaps compute only when fused.
// LDS map (57344 B): As@0(9216) | Gs@9216(13312) H1@22528(2x9216)
//   Ts overlays @9216 (2x13824; barrier before overlay write)
//   | Asm f32[4096]@40960(16384); Hp overlays @40960 ([98][72]=14112).
//   deg@9216, dinv@9472 (dead before Gs).  2 blocks/CU (114688 <= 160K).
// ---------------------------------------------------------------------------
__global__ __launch_bounds__(512, 4) void k_all(const float* __restrict__ x,
                                                const int* __restrict__ ei,
                                                const u16* __restrict__ W1b,
                                                const float* __restrict__ b1,
                                                const u16* __restrict__ W2b,
                                                const float* __restrict__ b2,
                                                const u16* __restrict__ Wcb,
                                                float* __restrict__ out) {
    const int b = blockIdx.x, t = threadIdx.x;
    const int w = t >> 6, lane = t & 63, quad = lane >> 4, l16 = lane & 15;
    const int wg = w & 3, wh = w >> 2;

    __shared__ __align__(16) char smem[57344];
    u16*   As   = (u16*)smem;                 // [64][72]
    u16*   Gs   = (u16*)(smem + 9216);        // [64][104]
    u16*   H1   = (u16*)(smem + 22528);       // [2][64][72]
    u16*   Ts   = (u16*)(smem + 9216);        // overlay: [2][96][72]
    float* Asm  = (float*)(smem + 40960);     // [64][64]
    u16*   Hp   = (u16*)(smem + 40960);       // overlay: [98][72]
    int*   deg  = (int*)(smem + 9216);
    float* dinv = (float*)(smem + 9472);

    // ---- phase 0: normalized adjacency ----
    for (int i = t; i < 4096; i += 512) Asm[i] = 0.f;
    if (t < 64) deg[t] = 1;                         // self loop
    __syncthreads();
    const int* eb = ei + (size_t)b * 2 * EE;
    const int es = eb[t], ed = eb[EE + t];          // E == 512 == blockDim
    atomicAdd(&deg[ed], 1);
    __syncthreads();
    if (t < 64) dinv[t] = rsqrtf((float)deg[t]);
    __syncthreads();
    atomicAdd(&Asm[ed * 64 + es], dinv[es] * dinv[ed]);
    if (t < 64) atomicAdd(&Asm[t * 64 + t], dinv[t] * dinv[t]);
    __syncthreads();
    // As bf16 [64][72]
    for (int i = t; i < 1024; i += 512) {
        int n = i >> 4, m4 = (i & 15) * 4;
        f32x4 v = *(const f32x4*)(Asm + n * 64 + m4);
        *(ushort4*)(As + n * 72 + m4) = packbf(v);
    }
    __syncthreads();

    // ---- MFMA0: Gs[node][s] = X @ A^T  (wave: ngroup=wg, s-half=wh) ----
    {
        short8 bf0[2];
        #pragma unroll
        for (int kc = 0; kc < 2; ++kc)
            bf0[kc] = ld8bf(As + (wg * 16 + l16) * 72 + kc * 32 + quad * 8);
        const float* xb = x + (size_t)b * SS * NN;
        #pragma unroll
        for (int jj = 0; jj < 3; ++jj) {
            const int j = wh * 3 + jj;
            f32x4 acc = (f32x4){0.f, 0.f, 0.f, 0.f};
            #pragma unroll
            for (int kc = 0; kc < 2; ++kc) {
                short8 a = cvt8(xb + (j * 16 + l16) * 64 + kc * 32 + quad * 8);
                acc = __builtin_amdgcn_mfma_f32_16x16x32_bf16(a, bf0[kc], acc, 0, 0, 0);
            }
            // col=l16 -> node=wg*16+l16 ; row=quad*4+r -> s=j*16+quad*4+r
            *(ushort4*)(Gs + (wg * 16 + l16) * 104 + j * 16 + quad * 4) = packbf(acc);
        }
    }
    __syncthreads();   // Gs cols written by both s-halves; chunk loop reads all 96

    // ---- hidden-chunk loop: wave handles hc = wh*4 .. wh*4+3 (barrier-free:
    //      H1 rows wave-private within each half's buffer) ----
    f32x4 accT[6];
    #pragma unroll
    for (int j = 0; j < 6; ++j) accT[j] = (f32x4){0.f, 0.f, 0.f, 0.f};

    short8 gb[3];
    #pragma unroll
    for (int kc = 0; kc < 3; ++kc)
        gb[kc] = ld8bf(Gs + (wg * 16 + l16) * 104 + kc * 32 + quad * 8);

    u16* H1w = H1 + wh * (64 * 72);
    #pragma unroll
    for (int hcc = 0; hcc < 4; ++hcc) {
        const int hc = wh * 4 + hcc;
        // MFMA1: C[h][node] -> H1w[node][h]
        #pragma unroll
        for (int hs = 0; hs < 4; ++hs) {
            f32x4 a1 = (f32x4){0.f, 0.f, 0.f, 0.f};
            #pragma unroll
            for (int kc = 0; kc < 3; ++kc) {
                short8 wa = ld8bf(W1b + (size_t)(hc * 64 + hs * 16 + l16) * 96 + kc * 32 + quad * 8);
                a1 = __builtin_amdgcn_mfma_f32_16x16x32_bf16(wa, gb[kc], a1, 0, 0, 0);
            }
            float4 bias = *(const float4*)(b1 + hc * 64 + hs * 16 + quad * 4);
            f32x4 r;
            r[0] = fmaxf(a1[0] + bias.x, 0.f); r[1] = fmaxf(a1[1] + bias.y, 0.f);
            r[2] = fmaxf(a1[2] + bias.z, 0.f); r[3] = fmaxf(a1[3] + bias.w, 0.f);
            *(ushort4*)(H1w + (wg * 16 + l16) * 72 + hs * 16 + quad * 4) = packbf(r);
        }
        // MFMA2: accT[node][s] += H1w @ W2c^T
        short8 ha[2];
        #pragma unroll
        for (int kc = 0; kc < 2; ++kc)
            ha[kc] = ld8bf(H1w + (wg * 16 + l16) * 72 + kc * 32 + quad * 8);
        #pragma unroll
        for (int j = 0; j < 6; ++j)
            #pragma unroll
            for (int kc = 0; kc < 2; ++kc) {
                short8 wb = ld8bf(W2b + (size_t)(j * 16 + l16) * HH + hc * 64 + kc * 32 + quad * 8);
                accT[j] = __builtin_amdgcn_mfma_f32_16x16x32_bf16(ha[kc], wb, accT[j], 0, 0, 0);
            }
    }

    // ---- Ts[wh][s][m] <- accT (overlay on Gs/H1: barrier first) ----
    __syncthreads();
    u16* Tsw = Ts + wh * (96 * 72);
    #pragma unroll
    for (int j = 0; j < 6; ++j)   // col=l16 -> s=j*16+l16 ; rows node=wg*16+quad*4+r
        *(ushort4*)(Tsw + (j * 16 + l16) * 72 + wg * 16 + quad * 4) = packbf(accT[j]);
    __syncthreads();

    // ---- MFMA3: Hp[s+1][n] = A @ (Ts0 + Ts1) + b2 ----
    {
        short8 af[2];
        #pragma unroll
        for (int kc = 0; kc < 2; ++kc)
            af[kc] = ld8bf(As + (wg * 16 + l16) * 72 + kc * 32 + quad * 8);
        #pragma unroll
        for (int jj = 0; jj < 3; ++jj) {
            const int j = wh * 3 + jj;
            f32x4 a3 = (f32x4){0.f, 0.f, 0.f, 0.f};
            #pragma unroll
            for (int h = 0; h < 2; ++h)
                #pragma unroll
                for (int kc = 0; kc < 2; ++kc) {
                    short8 tb = ld8bf(Ts + h * (96 * 72) + (j * 16 + l16) * 72 + kc * 32 + quad * 8);
                    a3 = __builtin_amdgcn_mfma_f32_16x16x32_bf16(af[kc], tb, a3, 0, 0, 0);
                }
            float bs = b2[j * 16 + l16];
            f32x4 r = {a3[0] + bs, a3[1] + bs, a3[2] + bs, a3[3] + bs};
            // col=l16 -> s=j*16+l16 ; rows n=wg*16+quad*4+r
            *(ushort4*)(Hp + (j * 16 + l16 + 1) * 72 + wg * 16 + quad * 4) = packbf(r);
        }
    }
    __syncthreads();
    if (t < 64) {                      // circular pad rows
        Hp[t] = Hp[96 * 72 + t];       // sp=0  <- s=95
        Hp[97 * 72 + t] = Hp[72 + t];  // sp=97 <- s=0
    }
    __syncthreads();

    // ---- conv: 8-wave split (wc = h-sub within ht, wt picks 4 ht-tiles) ----
    const int wc = w & 3, wt = w >> 2;
    float* ob = out + (size_t)b * SS * HH;
    #pragma unroll
    for (int htt = 0; htt < 4; ++htt) {
        const int ht = wt * 4 + htt;
        short8 wa[6];
        #pragma unroll
        for (int kc = 0; kc < 6; ++kc)
            wa[kc] = ld8bf(Wcb + (size_t)(ht * 64 + wc * 16 + l16) * 192 + kc * 32 + quad * 8);
        #pragma unroll
        for (int j = 0; j < 6; ++j) {
            f32x4 acc = (f32x4){0.f, 0.f, 0.f, 0.f};
            #pragma unroll
            for (int kc = 0; kc < 6; ++kc) {
                int kw = kc >> 1, nb = (kc & 1) * 32;
                short8 hb = ld8bf(Hp + (j * 16 + l16 + kw) * 72 + nb + quad * 8);
                acc = __builtin_amdgcn_mfma_f32_16x16x32_bf16(wa[kc], hb, acc, 0, 0, 0);
            }
            // col=l16 -> s=j*16+l16 ; rows h=ht*64+wc*16+quad*4+r
            float4 vv = {acc[0], acc[1], acc[2], acc[3]};
            *(float4*)(ob + (size_t)(j * 16 + l16) * HH + ht * 64 + wc * 16 + quad * 4) = vv;
        }
    }
}

// ---------------------------------------------------------------------------
extern "C" void kernel_launch(void* const* d_in, const int* in_sizes, int n_in,
                              void* d_out, int out_size, void* d_ws, size_t ws_size,
                              hipStream_t stream) {
    const float* x  = (const float*)d_in[0];
    const int*   ei = (const int*)d_in[1];
    const float* W1 = (const float*)d_in[2];
    const float* b1 = (const float*)d_in[3];
    const float* W2 = (const float*)d_in[4];
    const float* b2 = (const float*)d_in[5];
    const float* cw = (const float*)d_in[6];
    float* out = (float*)d_out;

    char* wsp = (char*)d_ws;                 // 384 KiB of workspace used
    u16* W1b = (u16*)wsp;                    // 98,304 B
    u16* W2b = (u16*)(wsp + 98304);          // 98,304 B
    u16* Wcb = (u16*)(wsp + 196608);         // 196,608 B

    k_prep<<<96, 256, 0, stream>>>(W1, W2, cw, W1b, W2b, Wcb);
    k_all <<<BB, 512, 0, stream>>>(x, ei, W1b, b1, W2b, b2, Wcb, out);
}

// Round 4
// 170.785 us; speedup vs baseline: 1.3268x; 1.0041x over previous
//
#include <hip/hip_runtime.h>
#include <hip/hip_bf16.h>

// Problem constants
#define BB 512   // batch
#define SS 96    // seq len
#define NN 64    // nodes
#define HH 512   // hidden
#define EE 512   // edges per graph

typedef __attribute__((ext_vector_type(8))) short short8;   // 8 bf16 (4 VGPRs)
typedef __attribute__((ext_vector_type(4))) float f32x4;    // MFMA acc
typedef unsigned short u16;

__device__ __forceinline__ u16 f2bf(float f) {
    union { float f; unsigned u; } v; v.f = f;
    return (u16)((v.u + 0x7FFFu + ((v.u >> 16) & 1u)) >> 16);   // RNE
}
__device__ __forceinline__ short8 ld8bf(const u16* p) { return *(const short8*)p; }
__device__ __forceinline__ short8 cvt8r(float4 a, float4 b) {  // 8 fp32 regs -> bf16 frag
    short8 r;
    r[0] = (short)f2bf(a.x); r[1] = (short)f2bf(a.y);
    r[2] = (short)f2bf(a.z); r[3] = (short)f2bf(a.w);
    r[4] = (short)f2bf(b.x); r[5] = (short)f2bf(b.y);
    r[6] = (short)f2bf(b.z); r[7] = (short)f2bf(b.w);
    return r;
}
__device__ __forceinline__ ushort4 packbf(f32x4 a) {
    ushort4 u; u.x = f2bf(a[0]); u.y = f2bf(a[1]); u.z = f2bf(a[2]); u.w = f2bf(a[3]);
    return u;
}

// ---------------------------------------------------------------------------
// k_prep: weights -> bf16; conv weight reordered (n,kw) -> (kw,n).
// ---------------------------------------------------------------------------
__global__ __launch_bounds__(256) void k_prep(const float* __restrict__ W1,
                                              const float* __restrict__ W2,
                                              const float* __restrict__ cw,
                                              u16* __restrict__ W1b,
                                              u16* __restrict__ W2b,
                                              u16* __restrict__ Wcb) {
    const int i0 = blockIdx.x * 256 + threadIdx.x, stp = gridDim.x * 256;
    for (int i = i0; i < HH * SS; i += stp) W1b[i] = f2bf(W1[i]);
    for (int i = i0; i < SS * HH; i += stp) W2b[i] = f2bf(W2[i]);
    for (int i = i0; i < HH * 192; i += stp) {
        int h = i / 192, q = i % 192, n = q / 3, kw = q % 3;
        Wcb[h * 192 + kw * 64 + n] = f2bf(cw[i]);
    }
}

// ---------------------------------------------------------------------------
// k_all: FUSED, one block of 512 threads (8 waves) per graph.
// Round-4 changes (chain-latency attack, VGPR stays <=128 so 2 blocks/CU):
//  (a) x fragments prefetched to registers at kernel entry (12 float4/wave);
//      their HBM/L3 latency hides under the phase-0 adjacency build.
//  (b) per-hcc W2b loads (12 short8) hoisted ABOVE MFMA1 - consumed ~1500cy
//      later, so their L2 latency is fully covered instead of serializing.
//  (c) circular-pad rows folded into MFMA3's stores (one barrier removed).
// LDS map (57344 B): As@0(9216) | Gs@9216(13312) H1@22528(2x9216)
//   Ts overlays @9216 (2x13824; barrier before overlay write)
//   | Asm f32[4096]@40960(16384); Hp overlays @40960 ([98][72]=14112).
//   deg@9216, dinv@9472 (dead before Gs).  2 blocks/CU (114688 <= 160K).
// ---------------------------------------------------------------------------
__global__ __launch_bounds__(512, 4) void k_all(const float* __restrict__ x,
                                                const int* __restrict__ ei,
                                                const u16* __restrict__ W1b,
                                                const float* __restrict__ b1,
                                                const u16* __restrict__ W2b,
                                                const float* __restrict__ b2,
                                                const u16* __restrict__ Wcb,
                                                float* __restrict__ out) {
    const int b = blockIdx.x, t = threadIdx.x;
    const int w = t >> 6, lane = t & 63, quad = lane >> 4, l16 = lane & 15;
    const int wg = w & 3, wh = w >> 2;

    __shared__ __align__(16) char smem[57344];
    u16*   As   = (u16*)smem;                 // [64][72]
    u16*   Gs   = (u16*)(smem + 9216);        // [64][104]
    u16*   H1   = (u16*)(smem + 22528);       // [2][64][72]
    u16*   Ts   = (u16*)(smem + 9216);        // overlay: [2][96][72]
    float* Asm  = (float*)(smem + 40960);     // [64][64]
    u16*   Hp   = (u16*)(smem + 40960);       // overlay: [98][72]
    int*   deg  = (int*)(smem + 9216);
    float* dinv = (float*)(smem + 9472);

    // ---- (a) x prefetch: issue BEFORE phase 0; latency hides under adjacency ----
    const float* xb = x + (size_t)b * SS * NN;
    float4 xp[3][2][2];   // [jj][kc][lo/hi] - fully static indexing
    #pragma unroll
    for (int jj = 0; jj < 3; ++jj)
        #pragma unroll
        for (int kc = 0; kc < 2; ++kc) {
            const float* p = xb + ((wh * 3 + jj) * 16 + l16) * 64 + kc * 32 + quad * 8;
            xp[jj][kc][0] = *(const float4*)p;
            xp[jj][kc][1] = *(const float4*)(p + 4);
        }

    // ---- phase 0: normalized adjacency ----
    for (int i = t; i < 4096; i += 512) Asm[i] = 0.f;
    if (t < 64) deg[t] = 1;                         // self loop
    __syncthreads();
    const int* eb = ei + (size_t)b * 2 * EE;
    const int es = eb[t], ed = eb[EE + t];          // E == 512 == blockDim
    atomicAdd(&deg[ed], 1);
    __syncthreads();
    if (t < 64) dinv[t] = rsqrtf((float)deg[t]);
    __syncthreads();
    atomicAdd(&Asm[ed * 64 + es], dinv[es] * dinv[ed]);
    if (t < 64) atomicAdd(&Asm[t * 64 + t], dinv[t] * dinv[t]);
    __syncthreads();
    // As bf16 [64][72]
    for (int i = t; i < 1024; i += 512) {
        int n = i >> 4, m4 = (i & 15) * 4;
        f32x4 v = *(const f32x4*)(Asm + n * 64 + m4);
        *(ushort4*)(As + n * 72 + m4) = packbf(v);
    }
    __syncthreads();

    // ---- MFMA0: Gs[node][s] = X @ A^T  (x already in registers) ----
    {
        short8 bf0[2];
        #pragma unroll
        for (int kc = 0; kc < 2; ++kc)
            bf0[kc] = ld8bf(As + (wg * 16 + l16) * 72 + kc * 32 + quad * 8);
        #pragma unroll
        for (int jj = 0; jj < 3; ++jj) {
            const int j = wh * 3 + jj;
            f32x4 acc = (f32x4){0.f, 0.f, 0.f, 0.f};
            #pragma unroll
            for (int kc = 0; kc < 2; ++kc) {
                short8 a = cvt8r(xp[jj][kc][0], xp[jj][kc][1]);
                acc = __builtin_amdgcn_mfma_f32_16x16x32_bf16(a, bf0[kc], acc, 0, 0, 0);
            }
            // col=l16 -> node=wg*16+l16 ; row=quad*4+r -> s=j*16+quad*4+r
            *(ushort4*)(Gs + (wg * 16 + l16) * 104 + j * 16 + quad * 4) = packbf(acc);
        }
    }
    __syncthreads();   // Gs cols written by both s-halves; chunk loop reads all 96

    // ---- hidden-chunk loop: wave handles hc = wh*4 .. wh*4+3 (barrier-free) ----
    f32x4 accT[6];
    #pragma unroll
    for (int j = 0; j < 6; ++j) accT[j] = (f32x4){0.f, 0.f, 0.f, 0.f};

    short8 gb[3];
    #pragma unroll
    for (int kc = 0; kc < 3; ++kc)
        gb[kc] = ld8bf(Gs + (wg * 16 + l16) * 104 + kc * 32 + quad * 8);

    u16* H1w = H1 + wh * (64 * 72);
    #pragma unroll
    for (int hcc = 0; hcc < 4; ++hcc) {
        const int hc = wh * 4 + hcc;
        // (b) hoist this iteration's W2b loads: consumed after MFMA1+H1 round
        // trip (~1500cy) -> L2 latency fully covered.  48 VGPR in flight.
        short8 w2r[6][2];
        #pragma unroll
        for (int j = 0; j < 6; ++j)
            #pragma unroll
            for (int kc = 0; kc < 2; ++kc)
                w2r[j][kc] = ld8bf(W2b + (size_t)(j * 16 + l16) * HH + hc * 64 + kc * 32 + quad * 8);
        // MFMA1: C[h][node] -> H1w[node][h]
        #pragma unroll
        for (int hs = 0; hs < 4; ++hs) {
            f32x4 a1 = (f32x4){0.f, 0.f, 0.f, 0.f};
            #pragma unroll
            for (int kc = 0; kc < 3; ++kc) {
                short8 wa = ld8bf(W1b + (size_t)(hc * 64 + hs * 16 + l16) * 96 + kc * 32 + quad * 8);
                a1 = __builtin_amdgcn_mfma_f32_16x16x32_bf16(wa, gb[kc], a1, 0, 0, 0);
            }
            float4 bias = *(const float4*)(b1 + hc * 64 + hs * 16 + quad * 4);
            f32x4 r;
            r[0] = fmaxf(a1[0] + bias.x, 0.f); r[1] = fmaxf(a1[1] + bias.y, 0.f);
            r[2] = fmaxf(a1[2] + bias.z, 0.f); r[3] = fmaxf(a1[3] + bias.w, 0.f);
            *(ushort4*)(H1w + (wg * 16 + l16) * 72 + hs * 16 + quad * 4) = packbf(r);
        }
        // MFMA2: accT[node][s] += H1w @ W2c^T (weights already in registers)
        short8 ha[2];
        #pragma unroll
        for (int kc = 0; kc < 2; ++kc)
            ha[kc] = ld8bf(H1w + (wg * 16 + l16) * 72 + kc * 32 + quad * 8);
        #pragma unroll
        for (int j = 0; j < 6; ++j)
            #pragma unroll
            for (int kc = 0; kc < 2; ++kc)
                accT[j] = __builtin_amdgcn_mfma_f32_16x16x32_bf16(ha[kc], w2r[j][kc], accT[j], 0, 0, 0);
    }

    // ---- Ts[wh][s][m] <- accT (overlay on Gs/H1: barrier first) ----
    __syncthreads();
    u16* Tsw = Ts + wh * (96 * 72);
    #pragma unroll
    for (int j = 0; j < 6; ++j)   // col=l16 -> s=j*16+l16 ; rows node=wg*16+quad*4+r
        *(ushort4*)(Tsw + (j * 16 + l16) * 72 + wg * 16 + quad * 4) = packbf(accT[j]);
    __syncthreads();

    // ---- MFMA3: Hp[s+1][n] = A @ (Ts0 + Ts1) + b2 ; pad rows folded in ----
    {
        short8 af[2];
        #pragma unroll
        for (int kc = 0; kc < 2; ++kc)
            af[kc] = ld8bf(As + (wg * 16 + l16) * 72 + kc * 32 + quad * 8);
        #pragma unroll
        for (int jj = 0; jj < 3; ++jj) {
            const int j = wh * 3 + jj;
            f32x4 a3 = (f32x4){0.f, 0.f, 0.f, 0.f};
            #pragma unroll
            for (int h = 0; h < 2; ++h)
                #pragma unroll
                for (int kc = 0; kc < 2; ++kc) {
                    short8 tb = ld8bf(Ts + h * (96 * 72) + (j * 16 + l16) * 72 + kc * 32 + quad * 8);
                    a3 = __builtin_amdgcn_mfma_f32_16x16x32_bf16(af[kc], tb, a3, 0, 0, 0);
                }
            float bs = b2[j * 16 + l16];
            f32x4 r = {a3[0] + bs, a3[1] + bs, a3[2] + bs, a3[3] + bs};
            ushort4 pr = packbf(r);
            // col=l16 -> s=j*16+l16 ; rows n=wg*16+quad*4+r
            *(ushort4*)(Hp + (j * 16 + l16 + 1) * 72 + wg * 16 + quad * 4) = pr;
            // (c) circular pad: row 0 <- s=95 ; row 97 <- s=0
            if (j == 5 && l16 == 15) *(ushort4*)(Hp + 0 * 72  + wg * 16 + quad * 4) = pr;
            if (j == 0 && l16 == 0)  *(ushort4*)(Hp + 97 * 72 + wg * 16 + quad * 4) = pr;
        }
    }
    __syncthreads();

    // ---- conv: 8-wave split (wc = h-sub within ht, wt picks 4 ht-tiles) ----
    const int wc = w & 3, wt = w >> 2;
    float* ob = out + (size_t)b * SS * HH;
    #pragma unroll
    for (int htt = 0; htt < 4; ++htt) {
        const int ht = wt * 4 + htt;
        short8 wa[6];
        #pragma unroll
        for (int kc = 0; kc < 6; ++kc)
            wa[kc] = ld8bf(Wcb + (size_t)(ht * 64 + wc * 16 + l16) * 192 + kc * 32 + quad * 8);
        #pragma unroll
        for (int j = 0; j < 6; ++j) {
            f32x4 acc = (f32x4){0.f, 0.f, 0.f, 0.f};
            #pragma unroll
            for (int kc = 0; kc < 6; ++kc) {
                int kw = kc >> 1, nb = (kc & 1) * 32;
                short8 hb = ld8bf(Hp + (j * 16 + l16 + kw) * 72 + nb + quad * 8);
                acc = __builtin_amdgcn_mfma_f32_16x16x32_bf16(wa[kc], hb, acc, 0, 0, 0);
            }
            // col=l16 -> s=j*16+l16 ; rows h=ht*64+wc*16+quad*4+r
            float4 vv = {acc[0], acc[1], acc[2], acc[3]};
            *(float4*)(ob + (size_t)(j * 16 + l16) * HH + ht * 64 + wc * 16 + quad * 4) = vv;
        }
    }
}

// ---------------------------------------------------------------------------
extern "C" void kernel_launch(void* const* d_in, const int* in_sizes, int n_in,
                              void* d_out, int out_size, void* d_ws, size_t ws_size,
                              hipStream_t stream) {
    const float* x  = (const float*)d_in[0];
    const int*   ei = (const int*)d_in[1];
    const float* W1 = (const float*)d_in[2];
    const float* b1 = (const float*)d_in[3];
    const float* W2 = (const float*)d_in[4];
    const float* b2 = (const float*)d_in[5];
    const float* cw = (const float*)d_in[6];
    float* out = (float*)d_out;

    char* wsp = (char*)d_ws;                 // 384 KiB of workspace used
    u16* W1b = (u16*)wsp;                    // 98,304 B
    u16* W2b = (u16*)(wsp + 98304);          // 98,304 B
    u16* Wcb = (u16*)(wsp + 196608);         // 196,608 B

    k_prep<<<96, 256, 0, stream>>>(W1, W2, cw, W1b, W2b, Wcb);
    k_all <<<BB, 512, 0, stream>>>(x, ei, W1b, b1, W2b, b2, Wcb, out);
}